// Round 2
// baseline (5545.377 us; speedup 1.0000x reference)
//
#include <hip/hip_runtime.h>
#include <stdint.h>

// LSTM: T=1024, B=32, I=512, H=512, fp32. Persistent-style, plain launch.
// R6 (from R4/R5 baseline 4929 us, VALUBusy 45%, HBM 2.8%):
//  a) x[t+1] prefetched into registers during step t -> phase 1 is pure LDS
//     writes; barrier A no longer drains a ~700-cycle global-load RT.
//  b) ring prefetch issues right after the (now cheap) barrier A -> the
//     publish->consume round trip gets ~700 more cycles of hiding under the
//     x-projection; straggler re-load sweeps become rare.
//  c) activation spread to 64 threads x 1 cell (was 32 x 2): halves the
//     serial transcendental chain; ring publish issued BEFORE out[] store.
// Ring protocol unchanged from R4: fused ((fp32_bits<<32)|tag) words, depth 4,
// relaxed agent-scope atomics, poison 0xAAAAAAAA != any tag (1..1024).
//
// 256 blocks = 4 batch-groups (bg) x 64 j-groups (jg). Weights in VGPRs for
// all 1024 steps. c-state block-local. out[] gets plain fp32 stores only.

#define T_STEPS 1024
#define BATCH   32
#define IDIM    512
#define HDIM    512

#define BG      4
#define JG      64
#define NBLK    (BG*JG)
#define BPB     (BATCH/BG)   // 8 batches/block
#define JPB     (HDIM/JG)    // 8 hidden units/block
#define RPB     (4*JPB)      // 32 gate rows/block
#define NTHR    256
#define PSTRIDE 257          // odd stride -> worst 2-way (free) LDS conflicts
#define RING_D  4
#define HWORDS  (BPB*HDIM)   // 4096 tagged words per (slot,bg)
#define WPT     (HWORDS/NTHR) // 16 words per consumer thread

__device__ __forceinline__ float sigmoid_f(float v) {
    return 1.0f / (1.0f + __expf(-v));
}
__device__ __forceinline__ float tanh_f(float v) {
    float e = __expf(2.0f * v);
    return 1.0f - 2.0f / (e + 1.0f);
}

__global__ __launch_bounds__(NTHR, 1) void lstm_persistent(
    const float* __restrict__ x,     // [T][B][I]
    const float* __restrict__ h0,    // [B][H]
    const float* __restrict__ c0,    // [B][H]
    const float* __restrict__ Wih,   // [4H][I]
    const float* __restrict__ Whh,   // [4H][H]
    const float* __restrict__ bih,   // [4H]
    const float* __restrict__ bhh,   // [4H]
    float* __restrict__ out,         // [T][B][H] ++ h_f[B][H] ++ c_f[B][H]
    unsigned long long* __restrict__ ring)  // [4][BG][HWORDS] tagged words
{
    __shared__ __align__(16) float xtile[BPB * IDIM];   // 16 KB
    __shared__ __align__(16) float htile[BPB * HDIM];   // 16 KB
    __shared__ float part[RPB * PSTRIDE];               // 32.9 KB
    __shared__ float garr[RPB * 9];
    __shared__ float biasl[RPB];

    const int tid = threadIdx.x;
    const int bid = blockIdx.x;
    const int bg  = bid >> 6;        // 0..3
    const int jg  = bid & 63;        // 0..63
    const int ks  = tid >> 3;        // 0..31 k-slice
    const int rq  = tid & 7;         // 0..7  row-quad

    // ---- weight slices -> registers (held for all steps) ----
    float4 wih[4][4], whh[4][4];
    #pragma unroll
    for (int r = 0; r < 4; ++r) {
        const int lr = rq * 4 + r;                                // 0..31
        const int grow = (lr >> 3) * HDIM + jg * JPB + (lr & 7);  // gate*512+j
        const float* wi = Wih + (size_t)grow * IDIM;
        const float* wh = Whh + (size_t)grow * HDIM;
        #pragma unroll
        for (int j = 0; j < 4; ++j) {
            const int k = ks * 4 + j * 128;
            wih[r][j] = *(const float4*)(wi + k);
            whh[r][j] = *(const float4*)(wh + k);
        }
    }
    if (tid < RPB) {
        const int grow = (tid >> 3) * HDIM + jg * JPB + (tid & 7);
        biasl[tid] = bih[grow] + bhh[grow];
    }

    // activation threads: 64 threads x 1 cell each
    const int ab = tid >> 3;          // batch 0..7 (tid<64)
    const int j1 = tid & 7;           // j within block slice
    float cst = 0.f, hl = 0.f;
    if (tid < 64) {
        cst = c0[(size_t)(bg * BPB + ab) * HDIM + jg * JPB + j1];
    }

    // x[0] prefetch into registers (phase-1 of every step is LDS-only)
    float4 xr[4];
    {
        const float* xsrc = x + (size_t)(bg * BPB) * IDIM;
        #pragma unroll
        for (int i = 0; i < 4; ++i)
            xr[i] = *(const float4*)(xsrc + i * 1024 + tid * 4);
    }
    __syncthreads();

    for (int t = 0; t < T_STEPS; ++t) {
        // ---- 1. stage x[t] from prefetch regs (conflict-free b128 writes) ----
        #pragma unroll
        for (int i = 0; i < 4; ++i)
            *(float4*)(xtile + i * 1024 + tid * 4) = xr[i];
        __syncthreads();   // A: xtile ready (LDS-only drain, cheap)

        // ---- 2a. prefetch tagged h(t-1) words (max hiding under x-proj) ----
        unsigned long long v[WPT];
        const unsigned int tag = (unsigned int)t;   // producers wrote (t-1)+1
        const unsigned long long* rb =
            ring + ((size_t)((t - 1) & 3) * BG + bg) * HWORDS;
        if (t > 0) {
            #pragma unroll
            for (int w = 0; w < WPT; ++w)
                v[w] = __hip_atomic_load(rb + w * NTHR + tid,
                                         __ATOMIC_RELAXED,
                                         __HIP_MEMORY_SCOPE_AGENT);
        }

        // ---- 2b. prefetch x[t+1] into regs (drains at next barrier D) ----
        if (t + 1 < T_STEPS) {
            const float* xsrc = x + ((size_t)(t + 1) * BATCH + bg * BPB) * IDIM;
            #pragma unroll
            for (int i = 0; i < 4; ++i)
                xr[i] = *(const float4*)(xsrc + i * 1024 + tid * 4);
        }

        // ---- 3. x projection ----
        float acc[4][BPB];
        #pragma unroll
        for (int r = 0; r < 4; ++r)
            #pragma unroll
            for (int b = 0; b < BPB; ++b) acc[r][b] = 0.0f;

        #pragma unroll
        for (int j = 0; j < 4; ++j) {
            #pragma unroll
            for (int b = 0; b < BPB; ++b) {
                const float4 vx = *(const float4*)(xtile + b * IDIM + ks * 4 + j * 128);
                #pragma unroll
                for (int r = 0; r < 4; ++r) {
                    acc[r][b] = fmaf(wih[r][j].x, vx.x, acc[r][b]);
                    acc[r][b] = fmaf(wih[r][j].y, vx.y, acc[r][b]);
                    acc[r][b] = fmaf(wih[r][j].z, vx.z, acc[r][b]);
                    acc[r][b] = fmaf(wih[r][j].w, vx.w, acc[r][b]);
                }
            }
        }

        // ---- 4. validate tags; reload stragglers; write h into htile ----
        if (t > 0) {
            for (int sweep = 0; sweep < 30000; ++sweep) {
                bool ok = true;
                #pragma unroll
                for (int w = 0; w < WPT; ++w) {
                    if ((unsigned int)v[w] != tag) {
                        v[w] = __hip_atomic_load(rb + w * NTHR + tid,
                                                 __ATOMIC_RELAXED,
                                                 __HIP_MEMORY_SCOPE_AGENT);
                        ok = false;
                    }
                }
                if (ok) break;                     // bail path -> visible error
                __builtin_amdgcn_s_sleep(1);
            }
            #pragma unroll
            for (int w = 0; w < WPT; ++w)
                htile[w * NTHR + tid] =
                    __uint_as_float((unsigned int)(v[w] >> 32));
        } else {
            const float* hsrc = h0 + (size_t)bg * BPB * HDIM;
            #pragma unroll
            for (int i = 0; i < 4; ++i) {
                const int f = i * 1024 + tid * 4;
                *(float4*)(htile + f) = *(const float4*)(hsrc + f);
            }
        }
        __syncthreads();   // D: htile ready (also drains xr prefetch, hidden)

        // ---- 5. h projection ----
        #pragma unroll
        for (int j = 0; j < 4; ++j) {
            #pragma unroll
            for (int b = 0; b < BPB; ++b) {
                const float4 vh = *(const float4*)(htile + b * HDIM + ks * 4 + j * 128);
                #pragma unroll
                for (int r = 0; r < 4; ++r) {
                    acc[r][b] = fmaf(whh[r][j].x, vh.x, acc[r][b]);
                    acc[r][b] = fmaf(whh[r][j].y, vh.y, acc[r][b]);
                    acc[r][b] = fmaf(whh[r][j].z, vh.z, acc[r][b]);
                    acc[r][b] = fmaf(whh[r][j].w, vh.w, acc[r][b]);
                }
            }
        }

        // ---- 6. spill partials ----
        #pragma unroll
        for (int r = 0; r < 4; ++r) {
            const int lr = rq * 4 + r;
            #pragma unroll
            for (int b = 0; b < BPB; ++b)
                part[lr * PSTRIDE + b * 32 + ks] = acc[r][b];
        }
        __syncthreads();   // E

        // ---- 7. reduce 32 k-slices ----
        {
            const int b  = tid >> 5;
            const int lr = tid & 31;
            const float* p = part + lr * PSTRIDE + b * 32;
            float s0 = 0.f, s1 = 0.f, s2 = 0.f, s3 = 0.f;
            #pragma unroll
            for (int k2 = 0; k2 < 32; k2 += 4) {
                s0 += p[k2]; s1 += p[k2 + 1]; s2 += p[k2 + 2]; s3 += p[k2 + 3];
            }
            garr[lr * 9 + b] = (s0 + s1) + (s2 + s3) + biasl[lr];
        }
        __syncthreads();   // F

        // ---- 8. activations, state update, publish (64 threads, 1 cell) ----
        if (tid < 64) {
            const float ig = sigmoid_f(garr[(0 * 8 + j1) * 9 + ab]);
            const float fg = sigmoid_f(garr[(1 * 8 + j1) * 9 + ab]);
            const float gg = tanh_f  (garr[(2 * 8 + j1) * 9 + ab]);
            const float og = sigmoid_f(garr[(3 * 8 + j1) * 9 + ab]);
            cst = fmaf(fg, cst, ig * gg);
            hl  = og * tanh_f(cst);

            // tagged ring publish FIRST (earliest visibility on serial chain)
            unsigned long long* rw = ring
                + ((size_t)(t & 3) * BG + bg) * HWORDS
                + ab * HDIM + jg * JPB + j1;
            __hip_atomic_store(rw,
                (((unsigned long long)__float_as_uint(hl)) << 32)
                    | (unsigned long long)(t + 1),
                __ATOMIC_RELAXED, __HIP_MEMORY_SCOPE_AGENT);

            // output store (plain; nobody reads out[] during the run)
            out[((size_t)t * BATCH + bg * BPB + ab) * HDIM + jg * JPB + j1] = hl;
        }
        // no barrier here: A/D/E/F already separate all cross-step hazards
    }

    // ---- final states h_f, c_f ----
    if (tid < 64) {
        const size_t base = (size_t)T_STEPS * BATCH * HDIM;
        const size_t off  = (size_t)(bg * BPB + ab) * HDIM + jg * JPB + j1;
        out[base + off] = hl;
        out[base + (size_t)BATCH * HDIM + off] = cst;
    }
}

extern "C" void kernel_launch(void* const* d_in, const int* in_sizes, int n_in,
                              void* d_out, int out_size, void* d_ws, size_t ws_size,
                              hipStream_t stream) {
    const float* x   = (const float*)d_in[0];
    const float* h0  = (const float*)d_in[1];
    const float* c0  = (const float*)d_in[2];
    const float* Wih = (const float*)d_in[3];
    const float* Whh = (const float*)d_in[4];
    const float* bih = (const float*)d_in[5];
    const float* bhh = (const float*)d_in[6];
    float* out = (float*)d_out;
    unsigned long long* ring = (unsigned long long*)d_ws;  // 512 KB; 0xAA poison
                                                           // != any tag -> no init
    lstm_persistent<<<dim3(NBLK), dim3(NTHR), 0, stream>>>(
        x, h0, c0, Wih, Whh, bih, bhh, out, ring);
}

// Round 3
// 3741.714 us; speedup vs baseline: 1.4820x; 1.4820x over previous
//
#include <hip/hip_runtime.h>
#include <stdint.h>

// LSTM: T=1024, B=32, I=512, H=512, fp32. Persistent-style, plain launch.
// R7 (post-mortem of R6 regression 4929->5545):
//  - REVERT R6's x-register-prefetch + early ring prefetch (made first-look
//    ring values staler -> more straggler sweeps; x-load drain at barrier A
//    was never on the critical path, it overlapped the peer-publish wait).
//  - NEW: 512 threads/block (8 waves -> 2 waves/SIMD, was 1). At 1 wave/SIMD
//    every LDS/L3 latency was fully exposed (VALUBusy 45%, 55% idle). Same
//    total work: each thread now owns 2 gate-rows (was 4), weights 64 VGPRs.
//  - KEEP R6's 64-thread x 1-cell activation (full wave 0, half the chain).
// Ring protocol unchanged from R4: fused ((fp32_bits<<32)|tag) words, depth 4,
// relaxed agent-scope atomics, poison 0xAAAAAAAA != any tag (1..1024).
//
// 256 blocks = 4 batch-groups (bg) x 64 j-groups (jg). Weights in VGPRs for
// all 1024 steps. c-state block-local. out[] gets plain fp32 stores only.

#define T_STEPS 1024
#define BATCH   32
#define IDIM    512
#define HDIM    512

#define BG      4
#define JG      64
#define NBLK    (BG*JG)
#define BPB     (BATCH/BG)   // 8 batches/block
#define JPB     (HDIM/JG)    // 8 hidden units/block
#define RPB     (4*JPB)      // 32 gate rows/block
#define NTHR    512          // 8 waves -> 2 waves/SIMD
#define PSTRIDE 257          // odd stride -> worst 2-way (free) LDS conflicts
#define RING_D  4
#define HWORDS  (BPB*HDIM)   // 4096 tagged words per (slot,bg)
#define WPT     (HWORDS/NTHR) // 8 words per consumer thread

__device__ __forceinline__ float sigmoid_f(float v) {
    return 1.0f / (1.0f + __expf(-v));
}
__device__ __forceinline__ float tanh_f(float v) {
    float e = __expf(2.0f * v);
    return 1.0f - 2.0f / (e + 1.0f);
}

__global__ __launch_bounds__(NTHR, 1) void lstm_persistent(
    const float* __restrict__ x,     // [T][B][I]
    const float* __restrict__ h0,    // [B][H]
    const float* __restrict__ c0,    // [B][H]
    const float* __restrict__ Wih,   // [4H][I]
    const float* __restrict__ Whh,   // [4H][H]
    const float* __restrict__ bih,   // [4H]
    const float* __restrict__ bhh,   // [4H]
    float* __restrict__ out,         // [T][B][H] ++ h_f[B][H] ++ c_f[B][H]
    unsigned long long* __restrict__ ring)  // [4][BG][HWORDS] tagged words
{
    __shared__ __align__(16) float xtile[BPB * IDIM];   // 16 KB
    __shared__ __align__(16) float htile[BPB * HDIM];   // 16 KB
    __shared__ float part[RPB * PSTRIDE];               // 32.9 KB
    __shared__ float garr[RPB * 9];
    __shared__ float biasl[RPB];

    const int tid = threadIdx.x;
    const int bid = blockIdx.x;
    const int bg  = bid >> 6;        // 0..3
    const int jg  = bid & 63;        // 0..63
    const int ks  = tid >> 4;        // 0..31 k-slice
    const int rp  = tid & 15;        // 0..15 row-pair

    // ---- weight slices -> registers (held for all steps) ----
    // each thread: 2 gate-rows x 16 k-elements (4 float4) per matrix
    float4 wih[2][4], whh[2][4];
    #pragma unroll
    for (int r = 0; r < 2; ++r) {
        const int lr = rp * 2 + r;                                // 0..31
        const int grow = (lr >> 3) * HDIM + jg * JPB + (lr & 7);  // gate*512+j
        const float* wi = Wih + (size_t)grow * IDIM;
        const float* wh = Whh + (size_t)grow * HDIM;
        #pragma unroll
        for (int j = 0; j < 4; ++j) {
            const int k = ks * 4 + j * 128;
            wih[r][j] = *(const float4*)(wi + k);
            whh[r][j] = *(const float4*)(wh + k);
        }
    }
    if (tid < RPB) {
        const int grow = (tid >> 3) * HDIM + jg * JPB + (tid & 7);
        biasl[tid] = bih[grow] + bhh[grow];
    }

    // activation threads: 64 threads (wave 0) x 1 cell each
    const int ab = tid >> 3;          // batch 0..7 (tid<64)
    const int j1 = tid & 7;           // j within block slice
    float cst = 0.f, hl = 0.f;
    if (tid < 64) {
        cst = c0[(size_t)(bg * BPB + ab) * HDIM + jg * JPB + j1];
    }
    __syncthreads();

    for (int t = 0; t < T_STEPS; ++t) {
        // ---- 1. stage x[t] (contiguous lane mapping, conflict-free) ----
        {
            const float* xsrc = x + ((size_t)t * BATCH + bg * BPB) * IDIM;
            #pragma unroll
            for (int i = 0; i < 2; ++i) {
                const int f = i * 2048 + tid * 4;
                *(float4*)(xtile + f) = *(const float4*)(xsrc + f);
            }
        }
        __syncthreads();   // A: xtile ready; also orders garr/part reuse

        // ---- 2. prefetch tagged h(t-1) words (RT hides under x-proj) ----
        unsigned long long v[WPT];
        const unsigned int tag = (unsigned int)t;   // producers wrote (t-1)+1
        const unsigned long long* rb =
            ring + ((size_t)((t - 1) & 3) * BG + bg) * HWORDS;
        if (t > 0) {
            #pragma unroll
            for (int w = 0; w < WPT; ++w)
                v[w] = __hip_atomic_load(rb + w * NTHR + tid,
                                         __ATOMIC_RELAXED,
                                         __HIP_MEMORY_SCOPE_AGENT);
        }

        // ---- 3. x projection ----
        float acc[2][BPB];
        #pragma unroll
        for (int r = 0; r < 2; ++r)
            #pragma unroll
            for (int b = 0; b < BPB; ++b) acc[r][b] = 0.0f;

        #pragma unroll
        for (int j = 0; j < 4; ++j) {
            #pragma unroll
            for (int b = 0; b < BPB; ++b) {
                const float4 vx = *(const float4*)(xtile + b * IDIM + ks * 4 + j * 128);
                #pragma unroll
                for (int r = 0; r < 2; ++r) {
                    acc[r][b] = fmaf(wih[r][j].x, vx.x, acc[r][b]);
                    acc[r][b] = fmaf(wih[r][j].y, vx.y, acc[r][b]);
                    acc[r][b] = fmaf(wih[r][j].z, vx.z, acc[r][b]);
                    acc[r][b] = fmaf(wih[r][j].w, vx.w, acc[r][b]);
                }
            }
        }

        // ---- 4. validate tags; reload stragglers; write h into htile ----
        if (t > 0) {
            for (int sweep = 0; sweep < 30000; ++sweep) {
                bool ok = true;
                #pragma unroll
                for (int w = 0; w < WPT; ++w) {
                    if ((unsigned int)v[w] != tag) {
                        v[w] = __hip_atomic_load(rb + w * NTHR + tid,
                                                 __ATOMIC_RELAXED,
                                                 __HIP_MEMORY_SCOPE_AGENT);
                        ok = false;
                    }
                }
                if (ok) break;                     // bail path -> visible error
                __builtin_amdgcn_s_sleep(1);
            }
            #pragma unroll
            for (int w = 0; w < WPT; ++w)
                htile[w * NTHR + tid] =
                    __uint_as_float((unsigned int)(v[w] >> 32));
        } else {
            const float* hsrc = h0 + (size_t)bg * BPB * HDIM;
            #pragma unroll
            for (int i = 0; i < 2; ++i) {
                const int f = i * 2048 + tid * 4;
                *(float4*)(htile + f) = *(const float4*)(hsrc + f);
            }
        }
        __syncthreads();   // D: htile ready

        // ---- 5. h projection ----
        #pragma unroll
        for (int j = 0; j < 4; ++j) {
            #pragma unroll
            for (int b = 0; b < BPB; ++b) {
                const float4 vh = *(const float4*)(htile + b * HDIM + ks * 4 + j * 128);
                #pragma unroll
                for (int r = 0; r < 2; ++r) {
                    acc[r][b] = fmaf(whh[r][j].x, vh.x, acc[r][b]);
                    acc[r][b] = fmaf(whh[r][j].y, vh.y, acc[r][b]);
                    acc[r][b] = fmaf(whh[r][j].z, vh.z, acc[r][b]);
                    acc[r][b] = fmaf(whh[r][j].w, vh.w, acc[r][b]);
                }
            }
        }

        // ---- 6. spill partials ----
        #pragma unroll
        for (int r = 0; r < 2; ++r) {
            const int lr = rp * 2 + r;
            #pragma unroll
            for (int b = 0; b < BPB; ++b)
                part[lr * PSTRIDE + b * 32 + ks] = acc[r][b];
        }
        __syncthreads();   // E

        // ---- 7. reduce 32 k-slices (first 256 threads) ----
        if (tid < 256) {
            const int b  = tid >> 5;
            const int lr = tid & 31;
            const float* p = part + lr * PSTRIDE + b * 32;
            float s0 = 0.f, s1 = 0.f, s2 = 0.f, s3 = 0.f;
            #pragma unroll
            for (int k2 = 0; k2 < 32; k2 += 4) {
                s0 += p[k2]; s1 += p[k2 + 1]; s2 += p[k2 + 2]; s3 += p[k2 + 3];
            }
            garr[lr * 9 + b] = (s0 + s1) + (s2 + s3) + biasl[lr];
        }
        __syncthreads();   // F

        // ---- 8. activations, state update, publish (64 threads, 1 cell) ----
        if (tid < 64) {
            const float ig = sigmoid_f(garr[(0 * 8 + j1) * 9 + ab]);
            const float fg = sigmoid_f(garr[(1 * 8 + j1) * 9 + ab]);
            const float gg = tanh_f  (garr[(2 * 8 + j1) * 9 + ab]);
            const float og = sigmoid_f(garr[(3 * 8 + j1) * 9 + ab]);
            cst = fmaf(fg, cst, ig * gg);
            hl  = og * tanh_f(cst);

            // tagged ring publish FIRST (earliest visibility on serial chain)
            unsigned long long* rw = ring
                + ((size_t)(t & 3) * BG + bg) * HWORDS
                + ab * HDIM + jg * JPB + j1;
            __hip_atomic_store(rw,
                (((unsigned long long)__float_as_uint(hl)) << 32)
                    | (unsigned long long)(t + 1),
                __ATOMIC_RELAXED, __HIP_MEMORY_SCOPE_AGENT);

            // output store (plain; nobody reads out[] during the run)
            out[((size_t)t * BATCH + bg * BPB + ab) * HDIM + jg * JPB + j1] = hl;
        }
        // no barrier here: A/D/E/F already separate all cross-step hazards
    }

    // ---- final states h_f, c_f ----
    if (tid < 64) {
        const size_t base = (size_t)T_STEPS * BATCH * HDIM;
        const size_t off  = (size_t)(bg * BPB + ab) * HDIM + jg * JPB + j1;
        out[base + off] = hl;
        out[base + (size_t)BATCH * HDIM + off] = cst;
    }
}

extern "C" void kernel_launch(void* const* d_in, const int* in_sizes, int n_in,
                              void* d_out, int out_size, void* d_ws, size_t ws_size,
                              hipStream_t stream) {
    const float* x   = (const float*)d_in[0];
    const float* h0  = (const float*)d_in[1];
    const float* c0  = (const float*)d_in[2];
    const float* Wih = (const float*)d_in[3];
    const float* Whh = (const float*)d_in[4];
    const float* bih = (const float*)d_in[5];
    const float* bhh = (const float*)d_in[6];
    float* out = (float*)d_out;
    unsigned long long* ring = (unsigned long long*)d_ws;  // 512 KB; 0xAA poison
                                                           // != any tag -> no init
    lstm_persistent<<<dim3(NBLK), dim3(NTHR), 0, stream>>>(
        x, h0, c0, Wih, Whh, bih, bhh, out, ring);
}